// Round 3
// baseline (314.223 us; speedup 1.0000x reference)
//
#include <hip/hip_runtime.h>
#include <math.h>

typedef _Float16 f16_t;
typedef _Float16 f16x8 __attribute__((ext_vector_type(8)));
typedef _Float16 f16x4 __attribute__((ext_vector_type(4)));
typedef _Float16 f16x2 __attribute__((ext_vector_type(2)));
typedef __fp16 h16x2 __attribute__((ext_vector_type(2)));
typedef float f32x4 __attribute__((ext_vector_type(4)));

#define LDS_BYTES 81920

// fp32 -> fp16 weights into d_ws, k-chunk-major with 16B-group swizzle baked in.
// Chunk ck = [256 n][32 k] (8192 f16 = 16 KB). Element (n, k=ck*32+q*8+j) at
// chunkBase + n*32 + (q ^ ((n>>1)&3))*8 + j.  Global chunk j=0..11: W1 ck0..3,
// then W2 ck0..7 -- one contiguous 12-chunk stream.
__global__ void wconv(const float* __restrict__ W1, const float* __restrict__ W2,
                      f16_t* __restrict__ o) {
  int i = blockIdx.x * 256 + threadIdx.x;  // 0..65535
  if (i < 32768) {
    int n = i >> 7, k = i & 127;
    int ck = k >> 5, q = (k >> 3) & 3, j = k & 7;
    o[ck * 8192 + n * 32 + (q ^ ((n >> 1) & 3)) * 8 + j] = (f16_t)W1[i];
  }
  {
    int n = i >> 8, k = i & 255;
    int ck = k >> 5, q = (k >> 3) & 3, j = k & 7;
    o[32768 + ck * 8192 + n * 32 + (q ^ ((n >> 1) & 3)) * 8 + j] = (f16_t)W2[i];
  }
}

__device__ __forceinline__ void stage16(const f16_t* g, f16_t* l) {
  __builtin_amdgcn_global_load_lds(
      (const __attribute__((address_space(1))) void*)g,
      (__attribute__((address_space(3))) void*)l, 16, 0, 0);
}

__device__ __forceinline__ f16x2 pk2(float a, float b) {
  union { h16x2 h; f16x2 f; } u;
  u.h = __builtin_amdgcn_cvt_pkrtz(a, b);
  return u.f;
}

#define COMP(v, r) ((r) == 0 ? (v).x : (r) == 1 ? (v).y : (r) == 2 ? (v).z : (v).w)

// Counted-vmcnt barriers. vmcnt(1) (NOT 2 -- round-2's vmcnt(2) was one too
// loose and relied on latency luck): with stages issued one per iter and two
// in flight, waiting to <=1 outstanding guarantees the chunk consumed THIS
// iter has landed, while the newest prefetch stays in flight across the barrier.
#define WAITBAR1() do { \
    asm volatile("s_waitcnt vmcnt(1) lgkmcnt(0)" ::: "memory"); \
    __builtin_amdgcn_s_barrier(); } while (0)
#define WAITBAR0() do { \
    asm volatile("s_waitcnt vmcnt(0) lgkmcnt(0)" ::: "memory"); \
    __builtin_amdgcn_s_barrier(); } while (0)
#define LGKMBAR() do { \
    asm volatile("s_waitcnt lgkmcnt(0)" ::: "memory"); \
    __builtin_amdgcn_s_barrier(); } while (0)

// Transposed fused MLP: D[feat][edge] = W @ x^T. Tile = 64 edges, 1024 threads,
// 16 waves as 8 feat-rows (32 feats) x 2 edge-cols (32 edges). acc[2][2] = 16
// regs/wave. Same tile work as the 512-thread version but 2x the waves: with
// 81920 B LDS x 2 blocks/CU (= 160 KiB exactly) and __launch_bounds__(1024,8)
// this targets 32 waves/CU (8/SIMD) -- double the latency hiding that rocprof
// showed was the limiter (28% issue-idle, no pipe >51%).
// Weights stream through a 3x16KB ring, prefetch depth 2, counted vmcnt(1).
// LN mean/rstd via a t<64 reduce into smean/srstd parked in ring slot 0's dead
// window (slot 0 untouched between barrier b5 and the j=4 stage of chunk 6).
__global__ __launch_bounds__(1024, 8) void fused_mlp(
    const float* __restrict__ h,
    const int* __restrict__ src,
    const int* __restrict__ dst,
    const f16_t* __restrict__ wks,
    const float* __restrict__ b1, const float* __restrict__ g1, const float* __restrict__ be1,
    const float* __restrict__ b2, const float* __restrict__ g2, const float* __restrict__ be2,
    const float* __restrict__ w3, const float* __restrict__ b3,
    float* __restrict__ out, int E, int nrows) {
  extern __shared__ __attribute__((aligned(16))) char smem[];
  f16_t* wlds = (f16_t*)smem;               // 3 x 8192 f16 ring (48 KB)
  f16_t* xbuf = (f16_t*)(smem + 49152);     // x0 [64][128]; later x1 [64][256] (32 KB)
  float* ssum1 = (float*)(smem + 65536);    // LN1 partials [8 wf][64 e] (x0-dead half)
  float* ssq1  = (float*)(smem + 67584);
  float* smean1 = (float*)(smem);           // [64] in ring slot 0 (dead b5..j=4 stage)
  float* srstd1 = (float*)(smem + 256);
  float* ssum2 = (float*)(smem);            // LN2 partials [8][64] in slot 0 (dead after j=9)
  float* ssq2  = (float*)(smem + 2048);
  float* smean2 = (float*)(smem + 4096);    // [64]
  float* srstd2 = (float*)(smem + 4352);
  float* pp = (float*)(smem + 8192);        // final partials [8][64]

  const int t = threadIdx.x;
  const int ebase = blockIdx.x * 64;

  auto stage_chunk = [&](int slot, int off) {  // 16 KB chunk, 1024 thr x 16 B
    stage16(wks + off + t * 8, wlds + slot * 8192 + t * 8);
  };

  stage_chunk(0, 0);      // chunk 0 (W1ck0)
  stage_chunk(1, 8192);   // chunk 1 (W1ck1)

  // ---------- gather: x0[m][k] = h[src][k]*h[dst][k], fp16, swizzled stride-128 ----
  // 16 threads per edge, 8 floats each -> one f16x8 group per thread.
  {
    const int m = t >> 4;   // edge 0..63
    const int j = t & 15;   // 8-float k-slice = k-group j
    const int e = ebase + m;
    f16_t* xrow = xbuf + m * 128;
    const int g0 = (j ^ (m & 15)) & 15;
    if (e < E) {
      int si = src[e], di = dst[e];
      si = ((unsigned)si < (unsigned)nrows) ? si : 0;
      di = ((unsigned)di < (unsigned)nrows) ? di : 0;
      const float* hs = h + (long long)si * 128 + j * 8;
      const float* hd = h + (long long)di * 128 + j * 8;
      const float4 a0 = *(const float4*)(hs);
      const float4 a1 = *(const float4*)(hs + 4);
      const float4 c0 = *(const float4*)(hd);
      const float4 c1 = *(const float4*)(hd + 4);
      union { f16x8 v8; f16x2 v2[4]; } u0;
      u0.v2[0] = pk2(a0.x * c0.x, a0.y * c0.y);
      u0.v2[1] = pk2(a0.z * c0.z, a0.w * c0.w);
      u0.v2[2] = pk2(a1.x * c1.x, a1.y * c1.y);
      u0.v2[3] = pk2(a1.z * c1.z, a1.w * c1.w);
      *(f16x8*)(xrow + g0 * 8) = u0.v8;
    } else {
      f16x8 z = {};
      *(f16x8*)(xrow + g0 * 8) = z;
    }
  }
  // gather's own VMEM data-dependency waits drain the two prologue stages
  // (in-order vmcnt), so chunk 0/1 are landed before iter 0's barrier.

  const int lane = t & 63;
  const int wave = t >> 6;   // 0..15
  const int wf = wave >> 1;  // 0..7: 32 feats each
  const int we = wave & 1;   // 0..1: 32 edges each
  const int c = lane & 15;
  const int q = lane >> 4;
  const int qp = q ^ ((c >> 1) & 3);  // weight-chunk swizzle (per-lane const)
  const int featBase = wf * 32;
  const int e0 = we * 32 + c, e1 = e0 + 16;
  const int woff = (featBase + c) * 32 + qp * 8;  // + msf*512, + slot*8192

  // ---------- GEMM1: K=128, global chunks 0..3 ----------
  f32x4 acc[2][2];
#pragma unroll
  for (int msf = 0; msf < 2; ++msf)
#pragma unroll
    for (int n = 0; n < 2; ++n) acc[msf][n] = (f32x4){0.f, 0.f, 0.f, 0.f};

#pragma unroll
  for (int j = 0; j < 4; ++j) {
    WAITBAR1();                                   // chunk j landed everywhere
    stage_chunk((j + 2) % 3, (j + 2) * 8192);     // prefetch chunk j+2
    const int rb = (j % 3) * 8192;
    const int gp = ((j * 4 + q) ^ c) & 15;
    f16x8 af[2], bf[2];
#pragma unroll
    for (int msf = 0; msf < 2; ++msf)
      af[msf] = *(const f16x8*)(wlds + rb + woff + msf * 512);
    bf[0] = *(const f16x8*)(xbuf + e0 * 128 + gp * 8);
    bf[1] = *(const f16x8*)(xbuf + e1 * 128 + gp * 8);
#pragma unroll
    for (int msf = 0; msf < 2; ++msf)
#pragma unroll
      for (int n = 0; n < 2; ++n)
        acc[msf][n] = __builtin_amdgcn_mfma_f32_16x16x32_f16(af[msf], bf[n], acc[msf][n], 0, 0, 0);
  }

  // ---------- LN1 stats ----------
  {
    float s0 = 0.f, s1 = 0.f, q0 = 0.f, q1 = 0.f;
#pragma unroll
    for (int msf = 0; msf < 2; ++msf) {
      const float4 bv = *(const float4*)(b1 + featBase + msf * 16 + q * 4);
#pragma unroll
      for (int r = 0; r < 4; ++r) {
        const float b = COMP(bv, r);
        float v0 = acc[msf][0][r] + b, v1 = acc[msf][1][r] + b;
        acc[msf][0][r] = v0; acc[msf][1][r] = v1;
        s0 += v0; q0 += v0 * v0;
        s1 += v1; q1 += v1 * v1;
      }
    }
    s0 += __shfl_xor(s0, 16, 64); s0 += __shfl_xor(s0, 32, 64);
    q0 += __shfl_xor(q0, 16, 64); q0 += __shfl_xor(q0, 32, 64);
    s1 += __shfl_xor(s1, 16, 64); s1 += __shfl_xor(s1, 32, 64);
    q1 += __shfl_xor(q1, 16, 64); q1 += __shfl_xor(q1, 32, 64);
    if (q == 0) {
      ssum1[wf * 64 + e0] = s0; ssq1[wf * 64 + e0] = q0;
      ssum1[wf * 64 + e1] = s1; ssq1[wf * 64 + e1] = q1;
    }
  }
  LGKMBAR();  // b5: partials visible; all chunk-3 / x0 reads drained

  if (t < 64) {
    float s = 0.f, sq = 0.f;
#pragma unroll
    for (int w = 0; w < 8; ++w) { s += ssum1[w * 64 + t]; sq += ssq1[w * 64 + t]; }
    float mu = s * (1.f / 256.f);
    float var = sq * (1.f / 256.f) - mu * mu;
    smean1[t] = mu;
    srstd1[t] = rsqrtf(var + 1e-5f);
  }
  LGKMBAR();  // b6: mean/rstd ready

  // ---------- LN1 normalize + ReLU -> x1 [64][256] (overwrites x0 + ssum1/ssq1) ----
  {
    const float rs0 = srstd1[e0], nmr0 = -smean1[e0] * rs0;
    const float rs1 = srstd1[e1], nmr1 = -smean1[e1] * rs1;
    const int j0 = (q & 1) * 4;
#pragma unroll
    for (int msf = 0; msf < 2; ++msf) {
      const float4 gv = *(const float4*)(g1 + featBase + msf * 16 + q * 4);
      const float4 bev = *(const float4*)(be1 + featBase + msf * 16 + q * 4);
      const int g = wf * 4 + msf * 2 + (q >> 1);  // feat 16B-group 0..31
      float v00, v01, v02, v03, v10, v11, v12, v13;
      v00 = fmaxf(fmaf(fmaf(acc[msf][0][0], rs0, nmr0), gv.x, bev.x), 0.f);
      v01 = fmaxf(fmaf(fmaf(acc[msf][0][1], rs0, nmr0), gv.y, bev.y), 0.f);
      v02 = fmaxf(fmaf(fmaf(acc[msf][0][2], rs0, nmr0), gv.z, bev.z), 0.f);
      v03 = fmaxf(fmaf(fmaf(acc[msf][0][3], rs0, nmr0), gv.w, bev.w), 0.f);
      v10 = fmaxf(fmaf(fmaf(acc[msf][1][0], rs1, nmr1), gv.x, bev.x), 0.f);
      v11 = fmaxf(fmaf(fmaf(acc[msf][1][1], rs1, nmr1), gv.y, bev.y), 0.f);
      v12 = fmaxf(fmaf(fmaf(acc[msf][1][2], rs1, nmr1), gv.z, bev.z), 0.f);
      v13 = fmaxf(fmaf(fmaf(acc[msf][1][3], rs1, nmr1), gv.w, bev.w), 0.f);
      union { f16x4 v4; f16x2 v2[2]; } h0, h1;
      h0.v2[0] = pk2(v00, v01); h0.v2[1] = pk2(v02, v03);
      h1.v2[0] = pk2(v10, v11); h1.v2[1] = pk2(v12, v13);
      const int gp0 = (g & 16) | ((g ^ e0) & 15);
      const int gp1 = (g & 16) | ((g ^ e1) & 15);
      *(f16x4*)(xbuf + e0 * 256 + gp0 * 8 + j0) = h0.v4;
      *(f16x4*)(xbuf + e1 * 256 + gp1 * 8 + j0) = h1.v4;
    }
  }

  // ---------- GEMM2: K=256, global chunks 4..11 ----------
  f32x4 acc2[2][2];
#pragma unroll
  for (int msf = 0; msf < 2; ++msf)
#pragma unroll
    for (int n = 0; n < 2; ++n) acc2[msf][n] = (f32x4){0.f, 0.f, 0.f, 0.f};

#pragma unroll
  for (int j = 4; j < 12; ++j) {
    if (j == 11) WAITBAR0(); else WAITBAR1();     // chunk j landed; x1 visible (j==4)
    if (j <= 9) stage_chunk((j + 2) % 3, (j + 2) * 8192);
    const int rb = (j % 3) * 8192;
    const int g = (j - 4) * 4 + q;  // 0..31
    const int gp0 = (g & 16) | ((g ^ e0) & 15);
    const int gp1 = (g & 16) | ((g ^ e1) & 15);
    f16x8 af[2], bf[2];
#pragma unroll
    for (int msf = 0; msf < 2; ++msf)
      af[msf] = *(const f16x8*)(wlds + rb + woff + msf * 512);
    bf[0] = *(const f16x8*)(xbuf + e0 * 256 + gp0 * 8);
    bf[1] = *(const f16x8*)(xbuf + e1 * 256 + gp1 * 8);
#pragma unroll
    for (int msf = 0; msf < 2; ++msf)
#pragma unroll
      for (int n = 0; n < 2; ++n)
        acc2[msf][n] = __builtin_amdgcn_mfma_f32_16x16x32_f16(af[msf], bf[n], acc2[msf][n], 0, 0, 0);
  }

  // ---------- LN2 stats (ring slot 0 dead: last read at iter 9) ----------
  {
    float s0 = 0.f, s1 = 0.f, q0 = 0.f, q1 = 0.f;
#pragma unroll
    for (int msf = 0; msf < 2; ++msf) {
      const float4 bv = *(const float4*)(b2 + featBase + msf * 16 + q * 4);
#pragma unroll
      for (int r = 0; r < 4; ++r) {
        const float b = COMP(bv, r);
        float v0 = acc2[msf][0][r] + b, v1 = acc2[msf][1][r] + b;
        acc2[msf][0][r] = v0; acc2[msf][1][r] = v1;
        s0 += v0; q0 += v0 * v0;
        s1 += v1; q1 += v1 * v1;
      }
    }
    s0 += __shfl_xor(s0, 16, 64); s0 += __shfl_xor(s0, 32, 64);
    q0 += __shfl_xor(q0, 16, 64); q0 += __shfl_xor(q0, 32, 64);
    s1 += __shfl_xor(s1, 16, 64); s1 += __shfl_xor(s1, 32, 64);
    q1 += __shfl_xor(q1, 16, 64); q1 += __shfl_xor(q1, 32, 64);
    if (q == 0) {
      ssum2[wf * 64 + e0] = s0; ssq2[wf * 64 + e0] = q0;
      ssum2[wf * 64 + e1] = s1; ssq2[wf * 64 + e1] = q1;
    }
  }
  LGKMBAR();  // b15

  if (t < 64) {
    float s = 0.f, sq = 0.f;
#pragma unroll
    for (int w = 0; w < 8; ++w) { s += ssum2[w * 64 + t]; sq += ssq2[w * 64 + t]; }
    float mu = s * (1.f / 256.f);
    float var = sq * (1.f / 256.f) - mu * mu;
    smean2[t] = mu;
    srstd2[t] = rsqrtf(var + 1e-5f);
  }
  LGKMBAR();  // b16

  // ---------- LN2 normalize + ReLU + dot(W3) + sigmoid ----------
  {
    const float rs0 = srstd2[e0], nmr0 = -smean2[e0] * rs0;
    const float rs1 = srstd2[e1], nmr1 = -smean2[e1] * rs1;
    float p0 = 0.f, p1 = 0.f;
#pragma unroll
    for (int msf = 0; msf < 2; ++msf) {
      const float4 gv = *(const float4*)(g2 + featBase + msf * 16 + q * 4);
      const float4 bev = *(const float4*)(be2 + featBase + msf * 16 + q * 4);
      const float4 wv = *(const float4*)(w3 + featBase + msf * 16 + q * 4);
#pragma unroll
      for (int r = 0; r < 4; ++r) {
        const float gr = COMP(gv, r), ber = COMP(bev, r), wr = COMP(wv, r);
        float v0 = fmaxf(fmaf(fmaf(acc2[msf][0][r], rs0, nmr0), gr, ber), 0.f);
        float v1 = fmaxf(fmaf(fmaf(acc2[msf][1][r], rs1, nmr1), gr, ber), 0.f);
        p0 = fmaf(v0, wr, p0);
        p1 = fmaf(v1, wr, p1);
      }
    }
    p0 += __shfl_xor(p0, 16, 64); p0 += __shfl_xor(p0, 32, 64);
    p1 += __shfl_xor(p1, 16, 64); p1 += __shfl_xor(p1, 32, 64);
    if (q == 0) {
      pp[wf * 64 + e0] = p0;
      pp[wf * 64 + e1] = p1;
    }
  }
  LGKMBAR();  // b17
  if (t < 64) {
    int e = ebase + t;
    if (e < E) {
      float sres = b3[0];
#pragma unroll
      for (int w = 0; w < 8; ++w) sres += pp[w * 64 + t];
      out[e] = 1.f / (1.f + __expf(-sres));
    }
  }
}

extern "C" void kernel_launch(void* const* d_in, const int* in_sizes, int n_in,
                              void* d_out, int out_size, void* d_ws, size_t ws_size,
                              hipStream_t stream) {
  const float* h = (const float*)d_in[0];
  const int* src = (const int*)d_in[1];
  const int* dst = (const int*)d_in[2];
  const float* W1 = (const float*)d_in[3];
  const float* b1 = (const float*)d_in[4];
  const float* g1 = (const float*)d_in[5];
  const float* be1 = (const float*)d_in[6];
  const float* W2 = (const float*)d_in[7];
  const float* b2 = (const float*)d_in[8];
  const float* g2 = (const float*)d_in[9];
  const float* be2 = (const float*)d_in[10];
  const float* W3 = (const float*)d_in[11];
  const float* b3 = (const float*)d_in[12];
  float* out = (float*)d_out;
  const int E = in_sizes[1];
  const int nrows = in_sizes[0] / 128;
  f16_t* wks = (f16_t*)d_ws;  // 98304 f16 = 196608 bytes

  wconv<<<256, 256, 0, stream>>>(W1, W2, wks);
  (void)hipFuncSetAttribute((const void*)fused_mlp,
                            hipFuncAttributeMaxDynamicSharedMemorySize, LDS_BYTES);
  const int tiles = (E + 63) / 64;
  fused_mlp<<<tiles, 1024, LDS_BYTES, stream>>>(h, src, dst, wks, b1, g1, be1,
                                                b2, g2, be2, W3, b3, out, E, nrows);
}

// Round 4
// 302.423 us; speedup vs baseline: 1.0390x; 1.0390x over previous
//
#include <hip/hip_runtime.h>
#include <math.h>

typedef _Float16 f16_t;
typedef _Float16 f16x8 __attribute__((ext_vector_type(8)));
typedef _Float16 f16x4 __attribute__((ext_vector_type(4)));
typedef _Float16 f16x2 __attribute__((ext_vector_type(2)));
typedef __fp16 h16x2 __attribute__((ext_vector_type(2)));
typedef float f32x4 __attribute__((ext_vector_type(4)));

#define LDS_BYTES 81920

// fp32 -> fp16 weights into d_ws, k-chunk-major with 16B-group swizzle baked in.
// Chunk ck = [256 n][32 k] (8192 f16 = 16 KB). Element (n, k=ck*32+q*8+j) at
// chunkBase + n*32 + (q ^ ((n>>1)&3))*8 + j.  Global chunk j=0..11: W1 ck0..3,
// then W2 ck0..7 -- one contiguous 12-chunk stream.
__global__ void wconv(const float* __restrict__ W1, const float* __restrict__ W2,
                      f16_t* __restrict__ o) {
  int i = blockIdx.x * 256 + threadIdx.x;  // 0..65535
  if (i < 32768) {
    int n = i >> 7, k = i & 127;
    int ck = k >> 5, q = (k >> 3) & 3, j = k & 7;
    o[ck * 8192 + n * 32 + (q ^ ((n >> 1) & 3)) * 8 + j] = (f16_t)W1[i];
  }
  {
    int n = i >> 8, k = i & 255;
    int ck = k >> 5, q = (k >> 3) & 3, j = k & 7;
    o[32768 + ck * 8192 + n * 32 + (q ^ ((n >> 1) & 3)) * 8 + j] = (f16_t)W2[i];
  }
}

__device__ __forceinline__ void stage16(const f16_t* g, f16_t* l) {
  __builtin_amdgcn_global_load_lds(
      (const __attribute__((address_space(1))) void*)g,
      (__attribute__((address_space(3))) void*)l, 16, 0, 0);
}

__device__ __forceinline__ f16x2 pk2(float a, float b) {
  union { h16x2 h; f16x2 f; } u;
  u.h = __builtin_amdgcn_cvt_pkrtz(a, b);
  return u.f;
}

#define COMP(v, r) ((r) == 0 ? (v).x : (r) == 1 ? (v).y : (r) == 2 ? (v).z : (v).w)

// Counted-vmcnt barriers: wait only for the chunk about to be consumed, leaving
// the newest prefetch in flight across the barrier.
#define WAITBAR1() do { \
    asm volatile("s_waitcnt vmcnt(1) lgkmcnt(0)" ::: "memory"); \
    __builtin_amdgcn_s_barrier(); } while (0)
#define WAITBAR0() do { \
    asm volatile("s_waitcnt vmcnt(0) lgkmcnt(0)" ::: "memory"); \
    __builtin_amdgcn_s_barrier(); } while (0)
#define LGKMBAR() do { \
    asm volatile("s_waitcnt lgkmcnt(0)" ::: "memory"); \
    __builtin_amdgcn_s_barrier(); } while (0)

// Transposed fused MLP: D[feat][edge] = W @ x^T. Tile = 64 edges, 1024 threads,
// 16 waves as 8 feat-rows (32 feats) x 2 edge-cols (32 edges). acc[2][2] = 16
// regs/wave.
// ROUND-4 CHANGE vs round 3: __launch_bounds__(1024) WITHOUT the min-waves=8
// clamp. Round 3's (1024,8) forced VGPR=32 < the ~48 live values -> scratch
// spills (WRITE_SIZE 2.5->117 MB, +~28us). Natural allocation for this per-wave
// footprint is ~44-48 VGPR (round-1 evidence: heavier per-wave code -> 48),
// which is <= 64, the threshold for 8 waves/SIMD -- so 2 blocks x 16 waves/CU
// co-residency (LDS 2 x 81920 = 160 KiB exactly) is preserved WITHOUT spills.
// Weights stream through a 3x16KB ring, prefetch depth 2, counted vmcnt(1).
__global__ __launch_bounds__(1024) void fused_mlp(
    const float* __restrict__ h,
    const int* __restrict__ src,
    const int* __restrict__ dst,
    const f16_t* __restrict__ wks,
    const float* __restrict__ b1, const float* __restrict__ g1, const float* __restrict__ be1,
    const float* __restrict__ b2, const float* __restrict__ g2, const float* __restrict__ be2,
    const float* __restrict__ w3, const float* __restrict__ b3,
    float* __restrict__ out, int E, int nrows) {
  extern __shared__ __attribute__((aligned(16))) char smem[];
  f16_t* wlds = (f16_t*)smem;               // 3 x 8192 f16 ring (48 KB)
  f16_t* xbuf = (f16_t*)(smem + 49152);     // x0 [64][128]; later x1 [64][256] (32 KB)
  float* ssum1 = (float*)(smem + 65536);    // LN1 partials [8 wf][64 e] (x0-dead half)
  float* ssq1  = (float*)(smem + 67584);
  float* smean1 = (float*)(smem);           // [64] in ring slot 0 (dead b5..j=4 stage)
  float* srstd1 = (float*)(smem + 256);
  float* ssum2 = (float*)(smem);            // LN2 partials [8][64] in slot 0 (dead after j=9)
  float* ssq2  = (float*)(smem + 2048);
  float* smean2 = (float*)(smem + 4096);    // [64]
  float* srstd2 = (float*)(smem + 4352);
  float* pp = (float*)(smem + 8192);        // final partials [8][64]

  const int t = threadIdx.x;
  const int ebase = blockIdx.x * 64;

  auto stage_chunk = [&](int slot, int off) {  // 16 KB chunk, 1024 thr x 16 B
    stage16(wks + off + t * 8, wlds + slot * 8192 + t * 8);
  };

  stage_chunk(0, 0);      // chunk 0 (W1ck0)
  stage_chunk(1, 8192);   // chunk 1 (W1ck1)

  // ---------- gather: x0[m][k] = h[src][k]*h[dst][k], fp16, swizzled stride-128 ----
  // 16 threads per edge, 8 floats each -> one f16x8 group per thread.
  {
    const int m = t >> 4;   // edge 0..63
    const int j = t & 15;   // 8-float k-slice = k-group j
    const int e = ebase + m;
    f16_t* xrow = xbuf + m * 128;
    const int g0 = (j ^ (m & 15)) & 15;
    if (e < E) {
      int si = src[e], di = dst[e];
      si = ((unsigned)si < (unsigned)nrows) ? si : 0;
      di = ((unsigned)di < (unsigned)nrows) ? di : 0;
      const float* hs = h + (long long)si * 128 + j * 8;
      const float* hd = h + (long long)di * 128 + j * 8;
      const float4 a0 = *(const float4*)(hs);
      const float4 a1 = *(const float4*)(hs + 4);
      const float4 c0 = *(const float4*)(hd);
      const float4 c1 = *(const float4*)(hd + 4);
      union { f16x8 v8; f16x2 v2[4]; } u0;
      u0.v2[0] = pk2(a0.x * c0.x, a0.y * c0.y);
      u0.v2[1] = pk2(a0.z * c0.z, a0.w * c0.w);
      u0.v2[2] = pk2(a1.x * c1.x, a1.y * c1.y);
      u0.v2[3] = pk2(a1.z * c1.z, a1.w * c1.w);
      *(f16x8*)(xrow + g0 * 8) = u0.v8;
    } else {
      f16x8 z = {};
      *(f16x8*)(xrow + g0 * 8) = z;
    }
  }
  // gather's own VMEM data-dependency waits drain the two prologue stages
  // (in-order vmcnt), so chunk 0/1 are landed before iter 0's barrier.

  const int lane = t & 63;
  const int wave = t >> 6;   // 0..15
  const int wf = wave >> 1;  // 0..7: 32 feats each
  const int we = wave & 1;   // 0..1: 32 edges each
  const int c = lane & 15;
  const int q = lane >> 4;
  const int qp = q ^ ((c >> 1) & 3);  // weight-chunk swizzle (per-lane const)
  const int featBase = wf * 32;
  const int e0 = we * 32 + c, e1 = e0 + 16;
  const int woff = (featBase + c) * 32 + qp * 8;  // + msf*512, + slot*8192

  // ---------- GEMM1: K=128, global chunks 0..3 ----------
  f32x4 acc[2][2];
#pragma unroll
  for (int msf = 0; msf < 2; ++msf)
#pragma unroll
    for (int n = 0; n < 2; ++n) acc[msf][n] = (f32x4){0.f, 0.f, 0.f, 0.f};

#pragma unroll
  for (int j = 0; j < 4; ++j) {
    WAITBAR1();                                   // chunk j landed everywhere
    stage_chunk((j + 2) % 3, (j + 2) * 8192);     // prefetch chunk j+2
    const int rb = (j % 3) * 8192;
    const int gp = ((j * 4 + q) ^ c) & 15;
    f16x8 af[2], bf[2];
#pragma unroll
    for (int msf = 0; msf < 2; ++msf)
      af[msf] = *(const f16x8*)(wlds + rb + woff + msf * 512);
    bf[0] = *(const f16x8*)(xbuf + e0 * 128 + gp * 8);
    bf[1] = *(const f16x8*)(xbuf + e1 * 128 + gp * 8);
#pragma unroll
    for (int msf = 0; msf < 2; ++msf)
#pragma unroll
      for (int n = 0; n < 2; ++n)
        acc[msf][n] = __builtin_amdgcn_mfma_f32_16x16x32_f16(af[msf], bf[n], acc[msf][n], 0, 0, 0);
  }

  // ---------- LN1 stats ----------
  {
    float s0 = 0.f, s1 = 0.f, q0 = 0.f, q1 = 0.f;
#pragma unroll
    for (int msf = 0; msf < 2; ++msf) {
      const float4 bv = *(const float4*)(b1 + featBase + msf * 16 + q * 4);
#pragma unroll
      for (int r = 0; r < 4; ++r) {
        const float b = COMP(bv, r);
        float v0 = acc[msf][0][r] + b, v1 = acc[msf][1][r] + b;
        acc[msf][0][r] = v0; acc[msf][1][r] = v1;
        s0 += v0; q0 += v0 * v0;
        s1 += v1; q1 += v1 * v1;
      }
    }
    s0 += __shfl_xor(s0, 16, 64); s0 += __shfl_xor(s0, 32, 64);
    q0 += __shfl_xor(q0, 16, 64); q0 += __shfl_xor(q0, 32, 64);
    s1 += __shfl_xor(s1, 16, 64); s1 += __shfl_xor(s1, 32, 64);
    q1 += __shfl_xor(q1, 16, 64); q1 += __shfl_xor(q1, 32, 64);
    if (q == 0) {
      ssum1[wf * 64 + e0] = s0; ssq1[wf * 64 + e0] = q0;
      ssum1[wf * 64 + e1] = s1; ssq1[wf * 64 + e1] = q1;
    }
  }
  LGKMBAR();  // b5: partials visible; all chunk-3 / x0 reads drained

  if (t < 64) {
    float s = 0.f, sq = 0.f;
#pragma unroll
    for (int w = 0; w < 8; ++w) { s += ssum1[w * 64 + t]; sq += ssq1[w * 64 + t]; }
    float mu = s * (1.f / 256.f);
    float var = sq * (1.f / 256.f) - mu * mu;
    smean1[t] = mu;
    srstd1[t] = rsqrtf(var + 1e-5f);
  }
  LGKMBAR();  // b6: mean/rstd ready

  // ---------- LN1 normalize + ReLU -> x1 [64][256] (overwrites x0 + ssum1/ssq1) ----
  {
    const float rs0 = srstd1[e0], nmr0 = -smean1[e0] * rs0;
    const float rs1 = srstd1[e1], nmr1 = -smean1[e1] * rs1;
    const int j0 = (q & 1) * 4;
#pragma unroll
    for (int msf = 0; msf < 2; ++msf) {
      const float4 gv = *(const float4*)(g1 + featBase + msf * 16 + q * 4);
      const float4 bev = *(const float4*)(be1 + featBase + msf * 16 + q * 4);
      const int g = wf * 4 + msf * 2 + (q >> 1);  // feat 16B-group 0..31
      float v00, v01, v02, v03, v10, v11, v12, v13;
      v00 = fmaxf(fmaf(fmaf(acc[msf][0][0], rs0, nmr0), gv.x, bev.x), 0.f);
      v01 = fmaxf(fmaf(fmaf(acc[msf][0][1], rs0, nmr0), gv.y, bev.y), 0.f);
      v02 = fmaxf(fmaf(fmaf(acc[msf][0][2], rs0, nmr0), gv.z, bev.z), 0.f);
      v03 = fmaxf(fmaf(fmaf(acc[msf][0][3], rs0, nmr0), gv.w, bev.w), 0.f);
      v10 = fmaxf(fmaf(fmaf(acc[msf][1][0], rs1, nmr1), gv.x, bev.x), 0.f);
      v11 = fmaxf(fmaf(fmaf(acc[msf][1][1], rs1, nmr1), gv.y, bev.y), 0.f);
      v12 = fmaxf(fmaf(fmaf(acc[msf][1][2], rs1, nmr1), gv.z, bev.z), 0.f);
      v13 = fmaxf(fmaf(fmaf(acc[msf][1][3], rs1, nmr1), gv.w, bev.w), 0.f);
      union { f16x4 v4; f16x2 v2[2]; } h0, h1;
      h0.v2[0] = pk2(v00, v01); h0.v2[1] = pk2(v02, v03);
      h1.v2[0] = pk2(v10, v11); h1.v2[1] = pk2(v12, v13);
      const int gp0 = (g & 16) | ((g ^ e0) & 15);
      const int gp1 = (g & 16) | ((g ^ e1) & 15);
      *(f16x4*)(xbuf + e0 * 256 + gp0 * 8 + j0) = h0.v4;
      *(f16x4*)(xbuf + e1 * 256 + gp1 * 8 + j0) = h1.v4;
    }
  }

  // ---------- GEMM2: K=256, global chunks 4..11 ----------
  f32x4 acc2[2][2];
#pragma unroll
  for (int msf = 0; msf < 2; ++msf)
#pragma unroll
    for (int n = 0; n < 2; ++n) acc2[msf][n] = (f32x4){0.f, 0.f, 0.f, 0.f};

#pragma unroll
  for (int j = 4; j < 12; ++j) {
    if (j == 11) WAITBAR0(); else WAITBAR1();     // chunk j landed; x1 visible (j==4)
    if (j <= 9) stage_chunk((j + 2) % 3, (j + 2) * 8192);
    const int rb = (j % 3) * 8192;
    const int g = (j - 4) * 4 + q;  // 0..31
    const int gp0 = (g & 16) | ((g ^ e0) & 15);
    const int gp1 = (g & 16) | ((g ^ e1) & 15);
    f16x8 af[2], bf[2];
#pragma unroll
    for (int msf = 0; msf < 2; ++msf)
      af[msf] = *(const f16x8*)(wlds + rb + woff + msf * 512);
    bf[0] = *(const f16x8*)(xbuf + e0 * 256 + gp0 * 8);
    bf[1] = *(const f16x8*)(xbuf + e1 * 256 + gp1 * 8);
#pragma unroll
    for (int msf = 0; msf < 2; ++msf)
#pragma unroll
      for (int n = 0; n < 2; ++n)
        acc2[msf][n] = __builtin_amdgcn_mfma_f32_16x16x32_f16(af[msf], bf[n], acc2[msf][n], 0, 0, 0);
  }

  // ---------- LN2 stats (ring slot 0 dead: last read at iter 9) ----------
  {
    float s0 = 0.f, s1 = 0.f, q0 = 0.f, q1 = 0.f;
#pragma unroll
    for (int msf = 0; msf < 2; ++msf) {
      const float4 bv = *(const float4*)(b2 + featBase + msf * 16 + q * 4);
#pragma unroll
      for (int r = 0; r < 4; ++r) {
        const float b = COMP(bv, r);
        float v0 = acc2[msf][0][r] + b, v1 = acc2[msf][1][r] + b;
        acc2[msf][0][r] = v0; acc2[msf][1][r] = v1;
        s0 += v0; q0 += v0 * v0;
        s1 += v1; q1 += v1 * v1;
      }
    }
    s0 += __shfl_xor(s0, 16, 64); s0 += __shfl_xor(s0, 32, 64);
    q0 += __shfl_xor(q0, 16, 64); q0 += __shfl_xor(q0, 32, 64);
    s1 += __shfl_xor(s1, 16, 64); s1 += __shfl_xor(s1, 32, 64);
    q1 += __shfl_xor(q1, 16, 64); q1 += __shfl_xor(q1, 32, 64);
    if (q == 0) {
      ssum2[wf * 64 + e0] = s0; ssq2[wf * 64 + e0] = q0;
      ssum2[wf * 64 + e1] = s1; ssq2[wf * 64 + e1] = q1;
    }
  }
  LGKMBAR();  // b15

  if (t < 64) {
    float s = 0.f, sq = 0.f;
#pragma unroll
    for (int w = 0; w < 8; ++w) { s += ssum2[w * 64 + t]; sq += ssq2[w * 64 + t]; }
    float mu = s * (1.f / 256.f);
    float var = sq * (1.f / 256.f) - mu * mu;
    smean2[t] = mu;
    srstd2[t] = rsqrtf(var + 1e-5f);
  }
  LGKMBAR();  // b16

  // ---------- LN2 normalize + ReLU + dot(W3) + sigmoid ----------
  {
    const float rs0 = srstd2[e0], nmr0 = -smean2[e0] * rs0;
    const float rs1 = srstd2[e1], nmr1 = -smean2[e1] * rs1;
    float p0 = 0.f, p1 = 0.f;
#pragma unroll
    for (int msf = 0; msf < 2; ++msf) {
      const float4 gv = *(const float4*)(g2 + featBase + msf * 16 + q * 4);
      const float4 bev = *(const float4*)(be2 + featBase + msf * 16 + q * 4);
      const float4 wv = *(const float4*)(w3 + featBase + msf * 16 + q * 4);
#pragma unroll
      for (int r = 0; r < 4; ++r) {
        const float gr = COMP(gv, r), ber = COMP(bev, r), wr = COMP(wv, r);
        float v0 = fmaxf(fmaf(fmaf(acc2[msf][0][r], rs0, nmr0), gr, ber), 0.f);
        float v1 = fmaxf(fmaf(fmaf(acc2[msf][1][r], rs1, nmr1), gr, ber), 0.f);
        p0 = fmaf(v0, wr, p0);
        p1 = fmaf(v1, wr, p1);
      }
    }
    p0 += __shfl_xor(p0, 16, 64); p0 += __shfl_xor(p0, 32, 64);
    p1 += __shfl_xor(p1, 16, 64); p1 += __shfl_xor(p1, 32, 64);
    if (q == 0) {
      pp[wf * 64 + e0] = p0;
      pp[wf * 64 + e1] = p1;
    }
  }
  LGKMBAR();  // b17
  if (t < 64) {
    int e = ebase + t;
    if (e < E) {
      float sres = b3[0];
#pragma unroll
      for (int w = 0; w < 8; ++w) sres += pp[w * 64 + t];
      out[e] = 1.f / (1.f + __expf(-sres));
    }
  }
}

extern "C" void kernel_launch(void* const* d_in, const int* in_sizes, int n_in,
                              void* d_out, int out_size, void* d_ws, size_t ws_size,
                              hipStream_t stream) {
  const float* h = (const float*)d_in[0];
  const int* src = (const int*)d_in[1];
  const int* dst = (const int*)d_in[2];
  const float* W1 = (const float*)d_in[3];
  const float* b1 = (const float*)d_in[4];
  const float* g1 = (const float*)d_in[5];
  const float* be1 = (const float*)d_in[6];
  const float* W2 = (const float*)d_in[7];
  const float* b2 = (const float*)d_in[8];
  const float* g2 = (const float*)d_in[9];
  const float* be2 = (const float*)d_in[10];
  const float* W3 = (const float*)d_in[11];
  const float* b3 = (const float*)d_in[12];
  float* out = (float*)d_out;
  const int E = in_sizes[1];
  const int nrows = in_sizes[0] / 128;
  f16_t* wks = (f16_t*)d_ws;  // 98304 f16 = 196608 bytes

  wconv<<<256, 256, 0, stream>>>(W1, W2, wks);
  (void)hipFuncSetAttribute((const void*)fused_mlp,
                            hipFuncAttributeMaxDynamicSharedMemorySize, LDS_BYTES);
  const int tiles = (E + 63) / 64;
  fused_mlp<<<tiles, 1024, LDS_BYTES, stream>>>(h, src, dst, wks, b1, g1, be1,
                                                b2, g2, be2, W3, b3, out, E, nrows);
}